// Round 1
// baseline (497.778 us; speedup 1.0000x reference)
//
#include <hip/hip_runtime.h>
#include <math.h>

#define ROWS 18496          // bt*J*N = 64*17*17
#define SCALE 0.17677669529663687f  // 1/sqrt(32)

typedef unsigned short ushort_t;
typedef __attribute__((ext_vector_type(8))) short short8;
typedef __attribute__((ext_vector_type(4))) float f32x4;

__device__ __forceinline__ void fma4(float4& d, float s, const float4& v) {
    d.x = fmaf(s, v.x, d.x); d.y = fmaf(s, v.y, d.y);
    d.z = fmaf(s, v.z, d.z); d.w = fmaf(s, v.w, d.w);
}
__device__ __forceinline__ float dot4(const float4& a, const float4& b) {
    return a.x*b.x + a.y*b.y + a.z*b.z + a.w*b.w;
}

__device__ __forceinline__ ushort_t f2bf(float x) {
    union { float f; unsigned u; } v; v.f = x;
    unsigned r = v.u + 0x7fffu + ((v.u >> 16) & 1u);
    return (ushort_t)(r >> 16);
}
__device__ __forceinline__ float bf2f(ushort_t b) {
    union { unsigned u; float f; } v; v.u = ((unsigned)b) << 16; return v.f;
}

__device__ __forceinline__ void gl_lds16(const void* g, void* l) {
    __builtin_amdgcn_global_load_lds(
        (const __attribute__((address_space(1))) void*)g,
        (__attribute__((address_space(3))) void*)l, 16, 0, 0);
}

__device__ __forceinline__ void store_hilo(ushort_t* yhi, ushort_t* ylo,
                                           size_t off, const float4& a)
{
    ushort4 h, l;
    h.x = f2bf(a.x); l.x = f2bf(a.x - bf2f(h.x));
    h.y = f2bf(a.y); l.y = f2bf(a.y - bf2f(h.y));
    h.z = f2bf(a.z); l.z = f2bf(a.z - bf2f(h.z));
    h.w = f2bf(a.w); l.w = f2bf(a.w - bf2f(h.w));
    *(ushort4*)&yhi[off] = h;
    *(ushort4*)&ylo[off] = l;
}

// ---------------- merged conversion kernel ----------------------------
__global__ __launch_bounds__(256) void k_cvt_xw(
    const float4* __restrict__ x, ushort4* __restrict__ xhi, ushort4* __restrict__ xlo,
    const float* __restrict__ W, ushort_t* __restrict__ bh, ushort_t* __restrict__ bl)
{
    if (blockIdx.x < 4624) {
        int i = blockIdx.x * 256 + threadIdx.x;
        float4 v = x[i];
        ushort4 h, l;
        h.x = f2bf(v.x); l.x = f2bf(v.x - bf2f(h.x));
        h.y = f2bf(v.y); l.y = f2bf(v.y - bf2f(h.y));
        h.z = f2bf(v.z); l.z = f2bf(v.z - bf2f(h.z));
        h.w = f2bf(v.w); l.w = f2bf(v.w - bf2f(h.w));
        xhi[i] = h; xlo[i] = l;
    } else {
        int o = blockIdx.x - 4624;   // 0..1279
        int kk = threadIdx.x;        // 0..255
        int col = (o & 255) * 5 + (o >> 8);
        float v = W[(size_t)kk * 1280 + col];
        ushort_t hh = f2bf(v);
        bh[(size_t)o * 256 + kk] = hh;
        bl[(size_t)o * 256 + kk] = f2bf(v - bf2f(hh));
    }
}

// Wp (768x256 f32) -> transposed bf16 [n][k]
__global__ __launch_bounds__(256) void k_cvt_wp(
    const float* __restrict__ W, ushort_t* __restrict__ bh, ushort_t* __restrict__ bl)
{
    int n = blockIdx.x;          // 0..255
    for (int k = threadIdx.x; k < 768; k += 256) {
        float v = W[(size_t)k * 256 + n];
        ushort_t h = f2bf(v);
        bh[(size_t)n * 768 + k] = h;
        bl[(size_t)n * 768 + k] = f2bf(v - bf2f(h));
    }
}

// ---------------- split-bf16 MFMA GEMM --------------------------------
template<int BM, int BN, int K, int MODE>
__global__ __launch_bounds__(256) void k_gemm(
    const ushort_t* __restrict__ Ahi, const ushort_t* __restrict__ Alo,
    const ushort_t* __restrict__ Bhi, const ushort_t* __restrict__ Blo,
    const float* __restrict__ aux,
    float* __restrict__ out)
{
    constexpr int MT = BM / 32;
    constexpr int NT = BN / 32;
    __shared__ __attribute__((aligned(16))) ushort_t sAh[BM * 32];
    __shared__ __attribute__((aligned(16))) ushort_t sAl[BM * 32];
    __shared__ __attribute__((aligned(16))) ushort_t sBh[BN * 32];
    __shared__ __attribute__((aligned(16))) ushort_t sBl[BN * 32];

    const int t = threadIdx.x;
    const int lane = t & 63;
    const int ln = lane & 15, quad = lane >> 4;
    const int wave = t >> 6;
    const int wm = wave >> 1, wn = wave & 1;
    const int m0 = blockIdx.y * BM, n0 = blockIdx.x * BN;

    f32x4 acc[MT][NT];
#pragma unroll
    for (int i = 0; i < MT; ++i)
#pragma unroll
        for (int j = 0; j < NT; ++j) acc[i][j] = (f32x4){0.f, 0.f, 0.f, 0.f};

    for (int kb = 0; kb < K; kb += 32) {
        __syncthreads();
#pragma unroll
        for (int s = t; s < BM * 4; s += 256) {
            int row = s >> 2, kc = s & 3;
            int gr = m0 + row; if (gr > ROWS - 1) gr = ROWS - 1;
            size_t gb = ((size_t)gr * K + kb) * 2 + kc * 16;
            int lb = (s & ~63) * 16;
            gl_lds16((const char*)Ahi + gb, (char*)sAh + lb);
            gl_lds16((const char*)Alo + gb, (char*)sAl + lb);
        }
#pragma unroll
        for (int s = t; s < BN * 4; s += 256) {
            int row = s >> 2, kc = s & 3;
            size_t gb = ((size_t)(n0 + row) * K + kb) * 2 + kc * 16;
            int lb = (s & ~63) * 16;
            gl_lds16((const char*)Bhi + gb, (char*)sBh + lb);
            gl_lds16((const char*)Blo + gb, (char*)sBl + lb);
        }
        __syncthreads();

        short8 ah[MT], al[MT], bh[NT], bl[NT];
#pragma unroll
        for (int i = 0; i < MT; ++i) {
            int off = (wm * (BM / 2) + i * 16 + ln) * 32 + quad * 8;
            ah[i] = *(const short8*)&sAh[off];
            al[i] = *(const short8*)&sAl[off];
        }
#pragma unroll
        for (int j = 0; j < NT; ++j) {
            int off = (wn * (BN / 2) + j * 16 + ln) * 32 + quad * 8;
            bh[j] = *(const short8*)&sBh[off];
            bl[j] = *(const short8*)&sBl[off];
        }
#pragma unroll
        for (int i = 0; i < MT; ++i)
#pragma unroll
            for (int j = 0; j < NT; ++j) {
                acc[i][j] = __builtin_amdgcn_mfma_f32_16x16x32_bf16(ah[i], bh[j], acc[i][j], 0, 0, 0);
                acc[i][j] = __builtin_amdgcn_mfma_f32_16x16x32_bf16(ah[i], bl[j], acc[i][j], 0, 0, 0);
                acc[i][j] = __builtin_amdgcn_mfma_f32_16x16x32_bf16(al[i], bh[j], acc[i][j], 0, 0, 0);
            }
    }

#pragma unroll
    for (int i = 0; i < MT; ++i) {
#pragma unroll
        for (int r = 0; r < 4; ++r) {
            int gm = m0 + wm * (BM / 2) + i * 16 + quad * 4 + r;
            if (gm >= ROWS) continue;
            if (MODE == 0) {
                int jn = gm % 289;
                const float* Mrow = &aux[(size_t)jn * 256];
#pragma unroll
                for (int j = 0; j < NT; ++j) {
                    int gn = n0 + wn * (BN / 2) + j * 16 + ln;
                    out[(size_t)gm * 1280 + gn] = acc[i][j][r] * Mrow[gn & 255];
                }
            } else {
#pragma unroll
                for (int j = 0; j < NT; ++j) {
                    int gn = n0 + wn * (BN / 2) + j * 16 + ln;
                    out[(size_t)gm * 256 + gn] = acc[i][j][r] + aux[gn];
                }
            }
        }
    }
}

// ---------------- fused attention: scores + softmaxes + all combines -----
// 512 threads/block (8 waves), one block per (b,h), grid 512.
// LDS unchanged at 64.7 KB -> 2 blocks/CU possible; __launch_bounds__(512,4)
// caps VGPR at 128 so 16 waves/CU can reside (vs <=10 before).
// Every phase re-partitioned so all 8 waves carry work:
//   P1: 578 score-row units (S rows 0..288 via t<289; V rows via t in
//       [289,512) and a second unit t+512 for t<66), 17 accumulators each.
//   P3: 580 units = 145 point-pairs x 4 col-quads (2 points/thread,
//       halves the dominant FMA chain vs the old 4-point/292-thread split).
//   P4/P5: 1156 per-(j,n,c4) units.
__global__ __launch_bounds__(512, 4) void k_att(
    const float* __restrict__ qkv5,
    const float* __restrict__ A_s, const float* __restrict__ A_v,
    const float* __restrict__ adjS, const float* __restrict__ adjV,
    ushort_t* __restrict__ yhi, ushort_t* __restrict__ ylo)
{
    __shared__ __attribute__((aligned(16))) float sm[16184];
    float* aS  = sm;            // 4913  [n][j][k]
    float* aV  = sm + 4913;     // 4913  [j][n][m]
    float* ebS = sm + 9826;     // 289
    float* ebV = sm + 10115;    // 289
    float* buf = sm + 10404;    // 289*20

    const int t  = threadIdx.x;
    const int bh = blockIdx.x;
    const int b  = bh >> 3, h = bh & 7;
    const size_t rowbase = (size_t)b * 289;

    // ---- P0: exp of symmetrized biases ----
    for (int idx = t; idx < 578; idx += 512) {
        int f = idx / 289, rem = idx % 289;
        int jj = rem / 17, kk = rem % 17;
        float bias;
        if (f == 0)
            bias = 0.5f * ((A_s[jj*17+kk] + adjS[jj*17+kk]) + (A_s[kk*17+jj] + adjS[kk*17+jj]));
        else
            bias = 0.5f * ((A_v[jj*17+kk] + adjV[jj*17+kk]) + (A_v[kk*17+jj] + adjV[kk*17+jj]));
        (f ? ebV : ebS)[rem] = expf(bias);
    }

    // ---- P1: raw scores. 578 row-units over 512 threads ----
    // unit u < 289: S-scores for q-row u  (aS[n][j][k], n=u%17, j=u/17)
    // unit u >=289: V-scores for q-row u-289 (aV[j][n][m])
    float accA[17], accB[17];
#pragma unroll
    for (int i = 0; i < 17; ++i) { accA[i] = 0.f; accB[i] = 0.f; }
    const int u2 = t + 512;                 // second unit, valid if < 578 (t<66)
    for (int ch = 0; ch < 2; ++ch) {
        __syncthreads();
        for (int idx = t; idx < 1156; idx += 512) {
            int p = idx >> 2, c = idx & 3;
            *(float4*)&buf[p * 20 + c * 4] =
                *(const float4*)&qkv5[(rowbase + p) * 1280 + 256 + h * 32 + ch * 16 + c * 4];
        }
        __syncthreads();
        {   // unit A (every thread)
            const bool isS = (t < 289);
            const int p = isS ? t : t - 289;
            const float* qp = &qkv5[(rowbase + p) * 1280 + h * 32 + ch * 16];
            float4 q0 = *(const float4*)&qp[0];
            float4 q1 = *(const float4*)&qp[4];
            float4 q2 = *(const float4*)&qp[8];
            float4 q3 = *(const float4*)&qp[12];
            const int a = p / 17, bb = p % 17;
            if (isS) {
#pragma unroll
                for (int kk = 0; kk < 17; ++kk) {
                    const float4* r = (const float4*)&buf[(kk * 17 + bb) * 20];
                    accA[kk] += dot4(q0, r[0]) + dot4(q1, r[1]) + dot4(q2, r[2]) + dot4(q3, r[3]);
                }
            } else {
#pragma unroll
                for (int mm = 0; mm < 17; ++mm) {
                    const float4* r = (const float4*)&buf[(a * 17 + mm) * 20];
                    accA[mm] += dot4(q0, r[0]) + dot4(q1, r[1]) + dot4(q2, r[2]) + dot4(q3, r[3]);
                }
            }
        }
        if (u2 < 578) {   // unit B: always a V-row (223..288), t<66
            const int p = u2 - 289;
            const float* qp = &qkv5[(rowbase + p) * 1280 + h * 32 + ch * 16];
            float4 q0 = *(const float4*)&qp[0];
            float4 q1 = *(const float4*)&qp[4];
            float4 q2 = *(const float4*)&qp[8];
            float4 q3 = *(const float4*)&qp[12];
            const int a = p / 17;
#pragma unroll
            for (int mm = 0; mm < 17; ++mm) {
                const float4* r = (const float4*)&buf[(a * 17 + mm) * 20];
                accB[mm] += dot4(q0, r[0]) + dot4(q1, r[1]) + dot4(q2, r[2]) + dot4(q3, r[3]);
            }
        }
    }
    {   // write-out
        if (t < 289) {
            const int a = t / 17, bb = t % 17;
#pragma unroll
            for (int kk = 0; kk < 17; ++kk) aS[bb * 289 + a * 17 + kk] = accA[kk] * SCALE;
        } else {
            const int p = t - 289;
            const int a = p / 17, bb = p % 17;
#pragma unroll
            for (int mm = 0; mm < 17; ++mm) aV[a * 289 + bb * 17 + mm] = accA[mm] * SCALE;
        }
        if (u2 < 578) {
            const int p = u2 - 289;
            const int a = p / 17, bb = p % 17;
#pragma unroll
            for (int mm = 0; mm < 17; ++mm) aV[a * 289 + bb * 17 + mm] = accB[mm] * SCALE;
        }
    }
    __syncthreads();

    // ---- P2: in-place unbiased softmax on all 578 rows ----
    for (int idx = t; idx < 578; idx += 512) {
        float* row = (idx < 289) ? &aS[idx * 17] : &aV[(idx - 289) * 17];
        float v[17];
#pragma unroll
        for (int kk = 0; kk < 17; ++kk) v[kk] = row[kk];
        float mx = v[0];
#pragma unroll
        for (int kk = 1; kk < 17; ++kk) mx = fmaxf(mx, v[kk]);
        float sum = 0.f;
#pragma unroll
        for (int kk = 0; kk < 17; ++kk) { v[kk] = expf(v[kk] - mx); sum += v[kk]; }
        float inv = 1.f / sum;
#pragma unroll
        for (int kk = 0; kk < 17; ++kk) row[kk] = v[kk] * inv;
    }
    // (no sync needed: P3's staging sync orders P2 before consumers)

    // ---- P3: x_vsv -> y cols 0..255. 580 units (2 points x c4 each) ----
    for (int ch = 0; ch < 2; ++ch) {
        __syncthreads();
        for (int idx = t; idx < 1156; idx += 512) {
            int p = idx >> 2, c = idx & 3;
            *(float4*)&buf[p * 20 + c * 4] =
                *(const float4*)&qkv5[(rowbase + p) * 1280 + 1024 + h * 32 + ch * 16 + c * 4];
        }
        __syncthreads();
        for (int u = t; u < 580; u += 512) {
            const int c4 = (u & 3) * 4;
            const int pb = (u >> 2) * 2;          // 0..288 step 2
            const int nv = (289 - pb < 2) ? 1 : 2;
            const int p1 = (pb + 1 > 288) ? 288 : pb + 1;
            const int jj0 = pb / 17, nn0 = pb % 17;
            const int jj1 = p1 / 17, nn1 = p1 % 17;
            float eV0[17], eV1[17];
            {
                const float* s0 = &aV[jj0 * 289 + nn0 * 17];
                const float* s1 = &aV[jj1 * 289 + nn1 * 17];
#pragma unroll
                for (int m = 0; m < 17; ++m) { eV0[m] = s0[m]; eV1[m] = s1[m]; }
            }
            float4 acc0 = {0,0,0,0}, acc1 = {0,0,0,0};
            for (int kk = 0; kk < 17; ++kk) {
                float4 tg0 = {0,0,0,0}, tg1 = {0,0,0,0};
#pragma unroll
                for (int m = 0; m < 17; ++m) {
                    float4 v = *(const float4*)&buf[(kk * 17 + m) * 20 + c4];
                    fma4(tg0, eV0[m], v);
                    fma4(tg1, eV1[m], v);
                }
                fma4(acc0, aS[nn0 * 289 + jj0 * 17 + kk], tg0);
                fma4(acc1, aS[nn1 * 289 + jj1 * 17 + kk], tg1);
            }
            store_hilo(yhi, ylo, (rowbase + pb) * 768 + h * 32 + ch * 16 + c4, acc0);
            if (nv == 2)
                store_hilo(yhi, ylo, (rowbase + pb + 1) * 768 + h * 32 + ch * 16 + c4, acc1);
        }
    }

    // ---- P4: x_vs (aS2 = normalize(aS*ebS)) -> y cols 256..511 ----------
    for (int ch = 0; ch < 2; ++ch) {
        __syncthreads();
        for (int idx = t; idx < 1156; idx += 512) {
            int p = idx >> 2, c = idx & 3;
            *(float4*)&buf[p * 20 + c * 4] =
                *(const float4*)&qkv5[(rowbase + p) * 1280 + 512 + h * 32 + ch * 16 + c * 4];
        }
        __syncthreads();
        for (int u = t; u < 1156; u += 512) {
            const int c4 = (u & 3) * 4, rest = u >> 2;   // rest 0..288
            const int n = rest % 17, j = rest / 17;
            float w[17];
            float s = 0.f;
            const float* as = &aS[n * 289 + j * 17];
            const float* eb = &ebS[j * 17];
#pragma unroll
            for (int kk = 0; kk < 17; ++kk) { w[kk] = as[kk] * eb[kk]; s += w[kk]; }
            const float inv = 1.f / s;
            float4 a0 = {0,0,0,0};
            for (int kk = 0; kk < 17; ++kk) {
                float4 v = *(const float4*)&buf[(kk * 17 + n) * 20 + c4];
                fma4(a0, w[kk], v);
            }
            a0.x *= inv; a0.y *= inv; a0.z *= inv; a0.w *= inv;
            store_hilo(yhi, ylo, (rowbase + j * 17 + n) * 768 + 256 + h * 32 + ch * 16 + c4, a0);
        }
    }

    // ---- P5: x_vv (aV2 = normalize(aV*ebV)) -> y cols 512..767 ----------
    for (int ch = 0; ch < 2; ++ch) {
        __syncthreads();
        for (int idx = t; idx < 1156; idx += 512) {
            int p = idx >> 2, c = idx & 3;
            *(float4*)&buf[p * 20 + c * 4] =
                *(const float4*)&qkv5[(rowbase + p) * 1280 + 768 + h * 32 + ch * 16 + c * 4];
        }
        __syncthreads();
        for (int u = t; u < 1156; u += 512) {
            const int c4 = (u & 3) * 4, rest = u >> 2;   // rest 0..288
            const int j = rest % 17, n = rest / 17;
            float w[17];
            float s = 0.f;
            const float* av = &aV[j * 289 + n * 17];
            const float* eb = &ebV[n * 17];
#pragma unroll
            for (int mm = 0; mm < 17; ++mm) { w[mm] = av[mm] * eb[mm]; s += w[mm]; }
            const float inv = 1.f / s;
            float4 a0 = {0,0,0,0};
            for (int mm = 0; mm < 17; ++mm) {
                float4 v = *(const float4*)&buf[(j * 17 + mm) * 20 + c4];
                fma4(a0, w[mm], v);
            }
            a0.x *= inv; a0.y *= inv; a0.z *= inv; a0.w *= inv;
            store_hilo(yhi, ylo, (rowbase + j * 17 + n) * 768 + 512 + h * 32 + ch * 16 + c4, a0);
        }
    }
}

extern "C" void kernel_launch(void* const* d_in, const int* in_sizes, int n_in,
                              void* d_out, int out_size, void* d_ws, size_t ws_size,
                              hipStream_t stream)
{
    const float* x    = (const float*)d_in[0];
    const float* A_s  = (const float*)d_in[1];
    const float* A_v  = (const float*)d_in[2];
    const float* Wqkv = (const float*)d_in[3];
    const float* Wp   = (const float*)d_in[4];
    const float* bp   = (const float*)d_in[5];
    const float* M    = (const float*)d_in[6];
    const float* adjS = (const float*)d_in[7];
    const float* adjV = (const float*)d_in[8];
    float* out = (float*)d_out;

    char* w = (char*)d_ws;
    float*    qkv5  = (float*)w;                          // 95 MB, dead after k_att
    ushort_t* wph   = (ushort_t*)w;                       // written after k_att
    ushort_t* wpl   = (ushort_t*)(w + 393216);
    char* R = w + 134946816;
    ushort_t* xhi = (ushort_t*)R;
    ushort_t* xlo = (ushort_t*)(R + 9469952);
    ushort_t* wqh = (ushort_t*)(R + 18939904);
    ushort_t* wql = (ushort_t*)(R + 19595264);
    ushort_t* yhi = (ushort_t*)R;                         // alias (after qkv gemm done)
    ushort_t* ylo = (ushort_t*)(R + 28422144);

    k_cvt_xw<<<dim3(5904), 256, 0, stream>>>((const float4*)x, (ushort4*)xhi, (ushort4*)xlo,
                                             Wqkv, wqh, wql);
    k_gemm<128, 128, 256, 0><<<dim3(10, 145), 256, 0, stream>>>(xhi, xlo, wqh, wql, M, qkv5);
    k_att<<<dim3(512), 512, 0, stream>>>(qkv5, A_s, A_v, adjS, adjV, yhi, ylo);
    k_cvt_wp<<<dim3(256), 256, 0, stream>>>(Wp, wph, wpl);
    k_gemm<128, 64, 768, 1><<<dim3(4, 145), 256, 0, stream>>>(yhi, ylo, wph, wpl, bp, out);
}

// Round 2
// 309.646 us; speedup vs baseline: 1.6076x; 1.6076x over previous
//
#include <hip/hip_runtime.h>
#include <math.h>

#define ROWS 18496          // bt*J*N = 64*17*17
#define SCALE 0.17677669529663687f  // 1/sqrt(32)

typedef unsigned short ushort_t;
typedef __attribute__((ext_vector_type(8))) short short8;
typedef __attribute__((ext_vector_type(4))) float f32x4;

__device__ __forceinline__ void fma4(float4& d, float s, const float4& v) {
    d.x = fmaf(s, v.x, d.x); d.y = fmaf(s, v.y, d.y);
    d.z = fmaf(s, v.z, d.z); d.w = fmaf(s, v.w, d.w);
}
__device__ __forceinline__ float dot4(const float4& a, const float4& b) {
    return a.x*b.x + a.y*b.y + a.z*b.z + a.w*b.w;
}

__device__ __forceinline__ ushort_t f2bf(float x) {
    union { float f; unsigned u; } v; v.f = x;
    unsigned r = v.u + 0x7fffu + ((v.u >> 16) & 1u);
    return (ushort_t)(r >> 16);
}
__device__ __forceinline__ float bf2f(ushort_t b) {
    union { unsigned u; float f; } v; v.u = ((unsigned)b) << 16; return v.f;
}

__device__ __forceinline__ void gl_lds16(const void* g, void* l) {
    __builtin_amdgcn_global_load_lds(
        (const __attribute__((address_space(1))) void*)g,
        (__attribute__((address_space(3))) void*)l, 16, 0, 0);
}

__device__ __forceinline__ void store_hilo(ushort_t* yhi, ushort_t* ylo,
                                           size_t off, const float4& a)
{
    ushort4 h, l;
    h.x = f2bf(a.x); l.x = f2bf(a.x - bf2f(h.x));
    h.y = f2bf(a.y); l.y = f2bf(a.y - bf2f(h.y));
    h.z = f2bf(a.z); l.z = f2bf(a.z - bf2f(h.z));
    h.w = f2bf(a.w); l.w = f2bf(a.w - bf2f(h.w));
    *(ushort4*)&yhi[off] = h;
    *(ushort4*)&ylo[off] = l;
}

// ---------------- merged conversion kernel ----------------------------
__global__ __launch_bounds__(256) void k_cvt_xw(
    const float4* __restrict__ x, ushort4* __restrict__ xhi, ushort4* __restrict__ xlo,
    const float* __restrict__ W, ushort_t* __restrict__ bh, ushort_t* __restrict__ bl)
{
    if (blockIdx.x < 4624) {
        int i = blockIdx.x * 256 + threadIdx.x;
        float4 v = x[i];
        ushort4 h, l;
        h.x = f2bf(v.x); l.x = f2bf(v.x - bf2f(h.x));
        h.y = f2bf(v.y); l.y = f2bf(v.y - bf2f(h.y));
        h.z = f2bf(v.z); l.z = f2bf(v.z - bf2f(h.z));
        h.w = f2bf(v.w); l.w = f2bf(v.w - bf2f(h.w));
        xhi[i] = h; xlo[i] = l;
    } else {
        int o = blockIdx.x - 4624;   // 0..1279
        int kk = threadIdx.x;        // 0..255
        int col = (o & 255) * 5 + (o >> 8);
        float v = W[(size_t)kk * 1280 + col];
        ushort_t hh = f2bf(v);
        bh[(size_t)o * 256 + kk] = hh;
        bl[(size_t)o * 256 + kk] = f2bf(v - bf2f(hh));
    }
}

// Wp (768x256 f32) -> transposed bf16 [n][k]
__global__ __launch_bounds__(256) void k_cvt_wp(
    const float* __restrict__ W, ushort_t* __restrict__ bh, ushort_t* __restrict__ bl)
{
    int n = blockIdx.x;          // 0..255
    for (int k = threadIdx.x; k < 768; k += 256) {
        float v = W[(size_t)k * 256 + n];
        ushort_t h = f2bf(v);
        bh[(size_t)n * 768 + k] = h;
        bl[(size_t)n * 768 + k] = f2bf(v - bf2f(h));
    }
}

// ---------------- split-bf16 MFMA GEMM --------------------------------
template<int BM, int BN, int K, int MODE>
__global__ __launch_bounds__(256) void k_gemm(
    const ushort_t* __restrict__ Ahi, const ushort_t* __restrict__ Alo,
    const ushort_t* __restrict__ Bhi, const ushort_t* __restrict__ Blo,
    const float* __restrict__ aux,
    float* __restrict__ out)
{
    constexpr int MT = BM / 32;
    constexpr int NT = BN / 32;
    __shared__ __attribute__((aligned(16))) ushort_t sAh[BM * 32];
    __shared__ __attribute__((aligned(16))) ushort_t sAl[BM * 32];
    __shared__ __attribute__((aligned(16))) ushort_t sBh[BN * 32];
    __shared__ __attribute__((aligned(16))) ushort_t sBl[BN * 32];

    const int t = threadIdx.x;
    const int lane = t & 63;
    const int ln = lane & 15, quad = lane >> 4;
    const int wave = t >> 6;
    const int wm = wave >> 1, wn = wave & 1;
    const int m0 = blockIdx.y * BM, n0 = blockIdx.x * BN;

    f32x4 acc[MT][NT];
#pragma unroll
    for (int i = 0; i < MT; ++i)
#pragma unroll
        for (int j = 0; j < NT; ++j) acc[i][j] = (f32x4){0.f, 0.f, 0.f, 0.f};

    for (int kb = 0; kb < K; kb += 32) {
        __syncthreads();
#pragma unroll
        for (int s = t; s < BM * 4; s += 256) {
            int row = s >> 2, kc = s & 3;
            int gr = m0 + row; if (gr > ROWS - 1) gr = ROWS - 1;
            size_t gb = ((size_t)gr * K + kb) * 2 + kc * 16;
            int lb = (s & ~63) * 16;
            gl_lds16((const char*)Ahi + gb, (char*)sAh + lb);
            gl_lds16((const char*)Alo + gb, (char*)sAl + lb);
        }
#pragma unroll
        for (int s = t; s < BN * 4; s += 256) {
            int row = s >> 2, kc = s & 3;
            size_t gb = ((size_t)(n0 + row) * K + kb) * 2 + kc * 16;
            int lb = (s & ~63) * 16;
            gl_lds16((const char*)Bhi + gb, (char*)sBh + lb);
            gl_lds16((const char*)Blo + gb, (char*)sBl + lb);
        }
        __syncthreads();

        short8 ah[MT], al[MT], bh[NT], bl[NT];
#pragma unroll
        for (int i = 0; i < MT; ++i) {
            int off = (wm * (BM / 2) + i * 16 + ln) * 32 + quad * 8;
            ah[i] = *(const short8*)&sAh[off];
            al[i] = *(const short8*)&sAl[off];
        }
#pragma unroll
        for (int j = 0; j < NT; ++j) {
            int off = (wn * (BN / 2) + j * 16 + ln) * 32 + quad * 8;
            bh[j] = *(const short8*)&sBh[off];
            bl[j] = *(const short8*)&sBl[off];
        }
#pragma unroll
        for (int i = 0; i < MT; ++i)
#pragma unroll
            for (int j = 0; j < NT; ++j) {
                acc[i][j] = __builtin_amdgcn_mfma_f32_16x16x32_bf16(ah[i], bh[j], acc[i][j], 0, 0, 0);
                acc[i][j] = __builtin_amdgcn_mfma_f32_16x16x32_bf16(ah[i], bl[j], acc[i][j], 0, 0, 0);
                acc[i][j] = __builtin_amdgcn_mfma_f32_16x16x32_bf16(al[i], bh[j], acc[i][j], 0, 0, 0);
            }
    }

#pragma unroll
    for (int i = 0; i < MT; ++i) {
#pragma unroll
        for (int r = 0; r < 4; ++r) {
            int gm = m0 + wm * (BM / 2) + i * 16 + quad * 4 + r;
            if (gm >= ROWS) continue;
            if (MODE == 0) {
                int jn = gm % 289;
                const float* Mrow = &aux[(size_t)jn * 256];
#pragma unroll
                for (int j = 0; j < NT; ++j) {
                    int gn = n0 + wn * (BN / 2) + j * 16 + ln;
                    out[(size_t)gm * 1280 + gn] = acc[i][j][r] * Mrow[gn & 255];
                }
            } else {
#pragma unroll
                for (int j = 0; j < NT; ++j) {
                    int gn = n0 + wn * (BN / 2) + j * 16 + ln;
                    out[(size_t)gm * 256 + gn] = acc[i][j][r] + aux[gn];
                }
            }
        }
    }
}

// ---------------- fused attention: scores + softmaxes + all combines -----
// 512 threads/block (8 waves), one block per (b,h), grid 512.
// LDS 64.7 KB -> 2 blocks/CU. NOTE: no min-waves arg in launch_bounds —
// round-1's (512,4) capped VGPR at 64 and spilled everything to scratch
// (FETCH_SIZE 56->493 MB, 2.2x slower). Compiler needs ~128 VGPRs here;
// at 128, 2 blocks/CU (16 waves) still fit.
__global__ __launch_bounds__(512) void k_att(
    const float* __restrict__ qkv5,
    const float* __restrict__ A_s, const float* __restrict__ A_v,
    const float* __restrict__ adjS, const float* __restrict__ adjV,
    ushort_t* __restrict__ yhi, ushort_t* __restrict__ ylo)
{
    __shared__ __attribute__((aligned(16))) float sm[16184];
    float* aS  = sm;            // 4913  [n][j][k]
    float* aV  = sm + 4913;     // 4913  [j][n][m]
    float* ebS = sm + 9826;     // 289
    float* ebV = sm + 10115;    // 289
    float* buf = sm + 10404;    // 289*20

    const int t  = threadIdx.x;
    const int bh = blockIdx.x;
    const int b  = bh >> 3, h = bh & 7;
    const size_t rowbase = (size_t)b * 289;

    // ---- P0: exp of symmetrized biases ----
    for (int idx = t; idx < 578; idx += 512) {
        int f = idx / 289, rem = idx % 289;
        int jj = rem / 17, kk = rem % 17;
        float bias;
        if (f == 0)
            bias = 0.5f * ((A_s[jj*17+kk] + adjS[jj*17+kk]) + (A_s[kk*17+jj] + adjS[kk*17+jj]));
        else
            bias = 0.5f * ((A_v[jj*17+kk] + adjV[jj*17+kk]) + (A_v[kk*17+jj] + adjV[kk*17+jj]));
        (f ? ebV : ebS)[rem] = expf(bias);
    }

    // ---- P1: raw scores. 578 row-units over 512 threads ----
    // unit u < 289: S-scores for q-row u  (aS[n][j][k], n=u%17, j=u/17)
    // unit u >=289: V-scores for q-row u-289 (aV[j][n][m])
    float accA[17], accB[17];
#pragma unroll
    for (int i = 0; i < 17; ++i) { accA[i] = 0.f; accB[i] = 0.f; }
    const int u2 = t + 512;                 // second unit, valid if < 578 (t<66)
    for (int ch = 0; ch < 2; ++ch) {
        __syncthreads();
        for (int idx = t; idx < 1156; idx += 512) {
            int p = idx >> 2, c = idx & 3;
            *(float4*)&buf[p * 20 + c * 4] =
                *(const float4*)&qkv5[(rowbase + p) * 1280 + 256 + h * 32 + ch * 16 + c * 4];
        }
        __syncthreads();
        {   // unit A (every thread)
            const bool isS = (t < 289);
            const int p = isS ? t : t - 289;
            const float* qp = &qkv5[(rowbase + p) * 1280 + h * 32 + ch * 16];
            float4 q0 = *(const float4*)&qp[0];
            float4 q1 = *(const float4*)&qp[4];
            float4 q2 = *(const float4*)&qp[8];
            float4 q3 = *(const float4*)&qp[12];
            const int a = p / 17, bb = p % 17;
            if (isS) {
#pragma unroll
                for (int kk = 0; kk < 17; ++kk) {
                    const float4* r = (const float4*)&buf[(kk * 17 + bb) * 20];
                    accA[kk] += dot4(q0, r[0]) + dot4(q1, r[1]) + dot4(q2, r[2]) + dot4(q3, r[3]);
                }
            } else {
#pragma unroll
                for (int mm = 0; mm < 17; ++mm) {
                    const float4* r = (const float4*)&buf[(a * 17 + mm) * 20];
                    accA[mm] += dot4(q0, r[0]) + dot4(q1, r[1]) + dot4(q2, r[2]) + dot4(q3, r[3]);
                }
            }
        }
        if (u2 < 578) {   // unit B: always a V-row (223..288), t<66
            const int p = u2 - 289;
            const float* qp = &qkv5[(rowbase + p) * 1280 + h * 32 + ch * 16];
            float4 q0 = *(const float4*)&qp[0];
            float4 q1 = *(const float4*)&qp[4];
            float4 q2 = *(const float4*)&qp[8];
            float4 q3 = *(const float4*)&qp[12];
            const int a = p / 17;
#pragma unroll
            for (int mm = 0; mm < 17; ++mm) {
                const float4* r = (const float4*)&buf[(a * 17 + mm) * 20];
                accB[mm] += dot4(q0, r[0]) + dot4(q1, r[1]) + dot4(q2, r[2]) + dot4(q3, r[3]);
            }
        }
    }
    {   // write-out
        if (t < 289) {
            const int a = t / 17, bb = t % 17;
#pragma unroll
            for (int kk = 0; kk < 17; ++kk) aS[bb * 289 + a * 17 + kk] = accA[kk] * SCALE;
        } else {
            const int p = t - 289;
            const int a = p / 17, bb = p % 17;
#pragma unroll
            for (int mm = 0; mm < 17; ++mm) aV[a * 289 + bb * 17 + mm] = accA[mm] * SCALE;
        }
        if (u2 < 578) {
            const int p = u2 - 289;
            const int a = p / 17, bb = p % 17;
#pragma unroll
            for (int mm = 0; mm < 17; ++mm) aV[a * 289 + bb * 17 + mm] = accB[mm] * SCALE;
        }
    }
    __syncthreads();

    // ---- P2: in-place unbiased softmax on all 578 rows ----
    for (int idx = t; idx < 578; idx += 512) {
        float* row = (idx < 289) ? &aS[idx * 17] : &aV[(idx - 289) * 17];
        float v[17];
#pragma unroll
        for (int kk = 0; kk < 17; ++kk) v[kk] = row[kk];
        float mx = v[0];
#pragma unroll
        for (int kk = 1; kk < 17; ++kk) mx = fmaxf(mx, v[kk]);
        float sum = 0.f;
#pragma unroll
        for (int kk = 0; kk < 17; ++kk) { v[kk] = expf(v[kk] - mx); sum += v[kk]; }
        float inv = 1.f / sum;
#pragma unroll
        for (int kk = 0; kk < 17; ++kk) row[kk] = v[kk] * inv;
    }
    // (no sync needed: P3's staging sync orders P2 before consumers)

    // ---- P3: x_vsv -> y cols 0..255. 580 units (2 points x c4 each) ----
    for (int ch = 0; ch < 2; ++ch) {
        __syncthreads();
        for (int idx = t; idx < 1156; idx += 512) {
            int p = idx >> 2, c = idx & 3;
            *(float4*)&buf[p * 20 + c * 4] =
                *(const float4*)&qkv5[(rowbase + p) * 1280 + 1024 + h * 32 + ch * 16 + c * 4];
        }
        __syncthreads();
        for (int u = t; u < 580; u += 512) {
            const int c4 = (u & 3) * 4;
            const int pb = (u >> 2) * 2;          // 0..288 step 2
            const int nv = (289 - pb < 2) ? 1 : 2;
            const int p1 = (pb + 1 > 288) ? 288 : pb + 1;
            const int jj0 = pb / 17, nn0 = pb % 17;
            const int jj1 = p1 / 17, nn1 = p1 % 17;
            float eV0[17], eV1[17];
            {
                const float* s0 = &aV[jj0 * 289 + nn0 * 17];
                const float* s1 = &aV[jj1 * 289 + nn1 * 17];
#pragma unroll
                for (int m = 0; m < 17; ++m) { eV0[m] = s0[m]; eV1[m] = s1[m]; }
            }
            float4 acc0 = {0,0,0,0}, acc1 = {0,0,0,0};
            for (int kk = 0; kk < 17; ++kk) {
                float4 tg0 = {0,0,0,0}, tg1 = {0,0,0,0};
#pragma unroll
                for (int m = 0; m < 17; ++m) {
                    float4 v = *(const float4*)&buf[(kk * 17 + m) * 20 + c4];
                    fma4(tg0, eV0[m], v);
                    fma4(tg1, eV1[m], v);
                }
                fma4(acc0, aS[nn0 * 289 + jj0 * 17 + kk], tg0);
                fma4(acc1, aS[nn1 * 289 + jj1 * 17 + kk], tg1);
            }
            store_hilo(yhi, ylo, (rowbase + pb) * 768 + h * 32 + ch * 16 + c4, acc0);
            if (nv == 2)
                store_hilo(yhi, ylo, (rowbase + pb + 1) * 768 + h * 32 + ch * 16 + c4, acc1);
        }
    }

    // ---- P4: x_vs (aS2 = normalize(aS*ebS)) -> y cols 256..511 ----------
    for (int ch = 0; ch < 2; ++ch) {
        __syncthreads();
        for (int idx = t; idx < 1156; idx += 512) {
            int p = idx >> 2, c = idx & 3;
            *(float4*)&buf[p * 20 + c * 4] =
                *(const float4*)&qkv5[(rowbase + p) * 1280 + 512 + h * 32 + ch * 16 + c * 4];
        }
        __syncthreads();
        for (int u = t; u < 1156; u += 512) {
            const int c4 = (u & 3) * 4, rest = u >> 2;   // rest 0..288
            const int n = rest % 17, j = rest / 17;
            float w[17];
            float s = 0.f;
            const float* as = &aS[n * 289 + j * 17];
            const float* eb = &ebS[j * 17];
#pragma unroll
            for (int kk = 0; kk < 17; ++kk) { w[kk] = as[kk] * eb[kk]; s += w[kk]; }
            const float inv = 1.f / s;
            float4 a0 = {0,0,0,0};
            for (int kk = 0; kk < 17; ++kk) {
                float4 v = *(const float4*)&buf[(kk * 17 + n) * 20 + c4];
                fma4(a0, w[kk], v);
            }
            a0.x *= inv; a0.y *= inv; a0.z *= inv; a0.w *= inv;
            store_hilo(yhi, ylo, (rowbase + j * 17 + n) * 768 + 256 + h * 32 + ch * 16 + c4, a0);
        }
    }

    // ---- P5: x_vv (aV2 = normalize(aV*ebV)) -> y cols 512..767 ----------
    for (int ch = 0; ch < 2; ++ch) {
        __syncthreads();
        for (int idx = t; idx < 1156; idx += 512) {
            int p = idx >> 2, c = idx & 3;
            *(float4*)&buf[p * 20 + c * 4] =
                *(const float4*)&qkv5[(rowbase + p) * 1280 + 768 + h * 32 + ch * 16 + c * 4];
        }
        __syncthreads();
        for (int u = t; u < 1156; u += 512) {
            const int c4 = (u & 3) * 4, rest = u >> 2;   // rest 0..288
            const int j = rest % 17, n = rest / 17;
            float w[17];
            float s = 0.f;
            const float* av = &aV[j * 289 + n * 17];
            const float* eb = &ebV[n * 17];
#pragma unroll
            for (int mm = 0; mm < 17; ++mm) { w[mm] = av[mm] * eb[mm]; s += w[mm]; }
            const float inv = 1.f / s;
            float4 a0 = {0,0,0,0};
            for (int mm = 0; mm < 17; ++mm) {
                float4 v = *(const float4*)&buf[(j * 17 + mm) * 20 + c4];
                fma4(a0, w[mm], v);
            }
            a0.x *= inv; a0.y *= inv; a0.z *= inv; a0.w *= inv;
            store_hilo(yhi, ylo, (rowbase + j * 17 + n) * 768 + 512 + h * 32 + ch * 16 + c4, a0);
        }
    }
}

extern "C" void kernel_launch(void* const* d_in, const int* in_sizes, int n_in,
                              void* d_out, int out_size, void* d_ws, size_t ws_size,
                              hipStream_t stream)
{
    const float* x    = (const float*)d_in[0];
    const float* A_s  = (const float*)d_in[1];
    const float* A_v  = (const float*)d_in[2];
    const float* Wqkv = (const float*)d_in[3];
    const float* Wp   = (const float*)d_in[4];
    const float* bp   = (const float*)d_in[5];
    const float* M    = (const float*)d_in[6];
    const float* adjS = (const float*)d_in[7];
    const float* adjV = (const float*)d_in[8];
    float* out = (float*)d_out;

    char* w = (char*)d_ws;
    float*    qkv5  = (float*)w;                          // 95 MB, dead after k_att
    ushort_t* wph   = (ushort_t*)w;                       // written after k_att
    ushort_t* wpl   = (ushort_t*)(w + 393216);
    char* R = w + 134946816;
    ushort_t* xhi = (ushort_t*)R;
    ushort_t* xlo = (ushort_t*)(R + 9469952);
    ushort_t* wqh = (ushort_t*)(R + 18939904);
    ushort_t* wql = (ushort_t*)(R + 19595264);
    ushort_t* yhi = (ushort_t*)R;                         // alias (after qkv gemm done)
    ushort_t* ylo = (ushort_t*)(R + 28422144);

    k_cvt_xw<<<dim3(5904), 256, 0, stream>>>((const float4*)x, (ushort4*)xhi, (ushort4*)xlo,
                                             Wqkv, wqh, wql);
    k_gemm<128, 128, 256, 0><<<dim3(10, 145), 256, 0, stream>>>(xhi, xlo, wqh, wql, M, qkv5);
    k_att<<<dim3(512), 512, 0, stream>>>(qkv5, A_s, A_v, adjS, adjV, yhi, ylo);
    k_cvt_wp<<<dim3(256), 256, 0, stream>>>(Wp, wph, wpl);
    k_gemm<128, 64, 768, 1><<<dim3(4, 145), 256, 0, stream>>>(yhi, ylo, wph, wpl, bp, out);
}